// Round 7
// baseline (816.722 us; speedup 1.0000x reference)
//
#include <hip/hip_runtime.h>

#define EPS_C 0.01f
#define NU    128
#define DIN   64
#define COUT  10
// 2*log2(e): folded into W, E_w, E_b so tanh arg arrives pre-scaled for exp2
#define TSCALE 2.8853900817779268f

typedef float    f32x4 __attribute__((ext_vector_type(4)));
typedef _Float16 f16x2 __attribute__((ext_vector_type(2)));
typedef _Float16 f16x4 __attribute__((ext_vector_type(4)));
typedef _Float16 f16x8 __attribute__((ext_vector_type(8)));

#define MFMA32(A, B, C) __builtin_amdgcn_mfma_f32_16x16x32_f16((A), (B), (C), 0, 0, 0)
// LDS-only barrier: vmcnt stays in flight across the per-step sync.
#define BAR() asm volatile("s_waitcnt lgkmcnt(0)\n\ts_barrier" ::: "memory")

static __device__ inline f16x8 pack8(float4 a, float4 b)
{
    f16x2 p0 = __builtin_bit_cast(f16x2, __builtin_amdgcn_cvt_pkrtz(a.x, a.y));
    f16x2 p1 = __builtin_bit_cast(f16x2, __builtin_amdgcn_cvt_pkrtz(a.z, a.w));
    f16x2 p2 = __builtin_bit_cast(f16x2, __builtin_amdgcn_cvt_pkrtz(b.x, b.y));
    f16x2 p3 = __builtin_bit_cast(f16x2, __builtin_amdgcn_cvt_pkrtz(b.z, b.w));
    f16x8 r;
    r[0] = p0[0]; r[1] = p0[1]; r[2] = p1[0]; r[3] = p1[1];
    r[4] = p2[0]; r[5] = p2[1]; r[6] = p3[0]; r[7] = p3[1];
    return r;
}

// Producer/consumer wave specialization (r5 post-mortem: pipes fully
// serialize with 1 wave/SIMD; per-step 1065 cyc ~= MFMA 390 + LDS 350 +
// VALU/trans 160 + sync 150 with NO overlap). vs r6: ALL barriers now in
// UNIFORM control flow (divergent barriers are UB and a hang risk).
// 8 waves, 512 thr. Wave w (0..3) = W-wave, wave w+4 = A-wave; the pair
// shares SIMD (w&3) and owns units [32w, 32w+32) = m-tiles 2w, 2w+1.
//   W-wave: wa = W h + z (8 MFMA), tanh (all trans), z(t+1) (4 MFMA),
//           x loaded DIRECTLY from global (xs staging deleted).
//   A-wave: h' A-chain in place (8 MFMA), combine h' += th, h-write.
// th handoff is POINTWISE (same lane, same reg on the partner wave): f32x4
// per m-tile through LDS, no shuffle. Two barriers per step:
//   P1: both read hB; W: wa+trans+th-write | A: A-MFMAs
//   P2: A: th-read+combine+h-write | W: z(t+1) MFMAs + x cvt/load
// Each phase pairs one wave's latency with the other's issue work.
// MT[][] holds WT (scaled) on W-waves, AT (unscaled) on A-waves.
// mfma_f32_16x16x32_f16 layouts (HW-verified rounds 0-5):
//   A-op: A[m = lane&15][k = quad*8 + j]
//   B-op: B[k = quad*8 + j][n = lane&15]
//   D   : D[row = quad*4 + reg][col = lane&15]
// h exchange: unit u = 32w+16mt+4q+r, batch lid ->
//   hbuf[np][kt=w][(2mt+(q>>1))*16+lid][4(q&1)+r]  (f16x4 write; reads are
//   linear ds_read_b128, conflict-free)
__global__ __launch_bounds__(512, 1)
void rnn_core(const float* __restrict__ x,
              const float* __restrict__ E_w, const float* __restrict__ E_b,
              const float* __restrict__ B_p, const float* __restrict__ C_p,
              const float* __restrict__ D_w, const float* __restrict__ D_b,
              float* __restrict__ out, int T)
{
    const int tid  = threadIdx.x;
    const int lane = tid & 63;
    const int wv   = tid >> 6;     // wave 0..7
    const int w4   = wv & 3;       // m-tile pair owner 0..3
    const bool isW = wv < 4;
    const int lid  = lane & 15;
    const int q    = lane >> 4;
    const int g    = blockIdx.x;   // batch group (16 rows)

    __shared__ __attribute__((aligned(16))) _Float16 hbuf[2][4][64][8]; // 8 KB
    __shared__ __attribute__((aligned(16))) float    thx[4][2][64][4];  // 8 KB
    __shared__ float hfin[16][NU + 4];

    // zero parity-0 h buffer (4 KB)
    if (tid < 256)
        ((float4*)&hbuf[0][0][0][0])[tid] = (float4){0.f, 0.f, 0.f, 0.f};

    // LDS byte bases (layout algebra verified r0-r5)
    char* hrb = (char*)hbuf + lane * 16;                       // +p*4096 +kt*1024
    char* hwb = (char*)hbuf
              + (w4 * 64 + (q >> 1) * 16 + lid) * 16 + (q & 1) * 8;  // +np*4096 +mt*512
    char* thb = (char*)thx + w4 * 2048 + lane * 16;            // +mt*1024

    const int nch = T >> 3;

    // x global base for this batch row (W-waves only use it)
    const float* xb = x + (size_t)(g * 16 + lid) * T * DIN;

#define LOADX(dst, tt)                                                        \
    {                                                                         \
        const float* xp_ = xb + (size_t)(tt) * DIN + q * 8;                   \
        dst[0] = *(const float4*)(xp_);                                       \
        dst[1] = *(const float4*)(xp_ + 4);                                   \
        dst[2] = *(const float4*)(xp_ + 32);                                  \
        dst[3] = *(const float4*)(xp_ + 36);                                  \
    }

    // ---- role state (role-specific pieces initialized under divergence,
    //      no barriers inside) ----
    f16x8 MT[2][4];              // WT (scaled) on W-waves, AT on A-waves
    f16x8 EF[2][2];              // W only
    f32x4 ebv[2];                // W only
    float4 xr[2][4];             // W only: f32 slots, x(t+2) in slot t&1
    f16x8  xf0, xf1;             // W only: f16 frags of x(t+1)
    f32x4  zc0, zc1;             // W only
    f32x4  hf[2] = {{0.f,0.f,0.f,0.f}, {0.f,0.f,0.f,0.f}};   // A only

    if (isW) {
        #pragma unroll
        for (int mt = 0; mt < 2; ++mt) {
            const int m = w4 * 32 + mt * 16 + lid;
            #pragma unroll
            for (int kt = 0; kt < 4; ++kt) {
                f16x8 fw;
                #pragma unroll
                for (int j = 0; j < 8; ++j) {
                    const int k  = kt * 32 + q * 8 + j;
                    const float dg = (k == m) ? 0.01f : 0.0f;
                    fw[j] = (_Float16)((C_p[k * NU + m] - 0.6f * C_p[m * NU + k] - dg) * TSCALE);
                }
                MT[mt][kt] = fw;
            }
            #pragma unroll
            for (int kt = 0; kt < 2; ++kt) {
                f16x8 fe;
                #pragma unroll
                for (int j = 0; j < 8; ++j)
                    fe[j] = (_Float16)(E_w[m * DIN + kt * 32 + q * 8 + j] * TSCALE);
                EF[mt][kt] = fe;
            }
            #pragma unroll
            for (int r = 0; r < 4; ++r)
                ebv[mt][r] = E_b[w4 * 32 + mt * 16 + q * 4 + r] * TSCALE;
        }
        // x/z pipeline prologue
        float4 t0[4];
        LOADX(t0, 0);                       // x(0)
        f16x8 a0 = pack8(t0[0], t0[1]);
        f16x8 a1 = pack8(t0[2], t0[3]);
        zc0 = ebv[0];
        zc0 = MFMA32(EF[0][0], a0, zc0);
        zc0 = MFMA32(EF[0][1], a1, zc0);
        zc1 = ebv[1];
        zc1 = MFMA32(EF[1][0], a0, zc1);
        zc1 = MFMA32(EF[1][1], a1, zc1);
        int t1 = (T > 1) ? 1 : 0;
        LOADX(t0, t1);                      // x(1)
        xf0 = pack8(t0[0], t0[1]);
        xf1 = pack8(t0[2], t0[3]);
        int t2 = (T > 2) ? 2 : T - 1;
        LOADX(xr[0], t2);                   // x(2) -> slot 0
    } else {
        #pragma unroll
        for (int mt = 0; mt < 2; ++mt) {
            const int m = w4 * 32 + mt * 16 + lid;
            #pragma unroll
            for (int kt = 0; kt < 4; ++kt) {
                f16x8 fa;
                #pragma unroll
                for (int j = 0; j < 8; ++j) {
                    const int k  = kt * 32 + q * 8 + j;
                    const float dg = (k == m) ? 0.01f : 0.0f;
                    fa[j] = (_Float16)(B_p[k * NU + m] - 0.6f * B_p[m * NU + k] - dg);
                }
                MT[mt][kt] = fa;
            }
        }
    }
    __syncthreads();   // uniform

    for (int c = 0; c < nch; ++c) {
        #pragma unroll
        for (int i = 0; i < 8; ++i) {
            const int t  = c * 8 + i;
            const int p  = i & 1;
            const int np = p ^ 1;
            const int s  = i & 1;          // slot holding x(t+2)

            // ---- P1 (uniform part): read hB ----
            f16x8 hB[4];
            #pragma unroll
            for (int kt = 0; kt < 4; ++kt)
                hB[kt] = *(const f16x8*)(hrb + p * 4096 + kt * 1024);

            if (isW) {
                // wa chains + tanh + th write
                f32x4 wa0 = zc0, wa1 = zc1;
                #pragma unroll
                for (int kt = 0; kt < 4; ++kt) {
                    wa0 = MFMA32(MT[0][kt], hB[kt], wa0);
                    wa1 = MFMA32(MT[1][kt], hB[kt], wa1);
                }
                f32x4 th0, th1;
                #pragma unroll
                for (int r = 0; r < 4; ++r) {
                    const float rc0 = __builtin_amdgcn_rcpf(__builtin_amdgcn_exp2f(wa0[r]) + 1.0f);
                    const float rc1 = __builtin_amdgcn_rcpf(__builtin_amdgcn_exp2f(wa1[r]) + 1.0f);
                    th0[r] = __builtin_fmaf(-2.0f, rc0, 1.0f);
                    th1[r] = __builtin_fmaf(-2.0f, rc1, 1.0f);
                }
                *(f32x4*)(thb)        = th0;
                *(f32x4*)(thb + 1024) = th1;
            } else {
                // A-chain in place on h'
                #pragma unroll
                for (int kt = 0; kt < 4; ++kt) {
                    hf[0] = MFMA32(MT[0][kt], hB[kt], hf[0]);
                    hf[1] = MFMA32(MT[1][kt], hB[kt], hf[1]);
                }
            }
            BAR();   // uniform

            if (isW) {
                // z(t+1) MFMAs; cvt x(t+2); issue x(t+3)
                f32x4 zn0 = ebv[0], zn1 = ebv[1];
                zn0 = MFMA32(EF[0][0], xf0, zn0);
                zn1 = MFMA32(EF[1][0], xf0, zn1);
                zn0 = MFMA32(EF[0][1], xf1, zn0);
                zn1 = MFMA32(EF[1][1], xf1, zn1);
                zc0 = zn0; zc1 = zn1;

                xf0 = pack8(xr[s][0], xr[s][1]);   // x(t+2) -> frags
                xf1 = pack8(xr[s][2], xr[s][3]);
                int t3 = t + 3; if (t3 >= T) t3 = T - 1;
                LOADX(xr[s ^ 1], t3);              // x(t+3) in flight
            } else {
                // th read (hidden by partner's z MFMAs), combine, h write
                f32x4 th0 = *(const f32x4*)(thb);
                f32x4 th1 = *(const f32x4*)(thb + 1024);
                hf[0] += th0;
                hf[1] += th1;
                #pragma unroll
                for (int mt = 0; mt < 2; ++mt) {
                    f16x2 lo = __builtin_bit_cast(f16x2,
                        __builtin_amdgcn_cvt_pkrtz(EPS_C * hf[mt][0], EPS_C * hf[mt][1]));
                    f16x2 hi = __builtin_bit_cast(f16x2,
                        __builtin_amdgcn_cvt_pkrtz(EPS_C * hf[mt][2], EPS_C * hf[mt][3]));
                    f16x4 nh;
                    nh[0] = lo[0]; nh[1] = lo[1]; nh[2] = hi[0]; nh[3] = hi[1];
                    *(f16x4*)(hwb + np * 4096 + mt * 512) = nh;
                }
            }
            BAR();   // uniform; vmcnt stays in flight
        }
    }

    // ---- final: A-waves stash h = eps*h'; uniform sync; output GEMM ----
    if (!isW) {
        #pragma unroll
        for (int mt = 0; mt < 2; ++mt)
            #pragma unroll
            for (int r = 0; r < 4; ++r)
                hfin[lid][w4 * 32 + mt * 16 + q * 4 + r] = EPS_C * hf[mt][r];
    }
    __syncthreads();   // uniform

    if (tid < 16 * COUT) {
        const int r  = tid / COUT;
        const int cc = tid - r * COUT;
        float acc = D_b[cc];
        #pragma unroll 8
        for (int u = 0; u < NU; ++u)
            acc = fmaf(hfin[r][u], D_w[cc * NU + u], acc);
        out[((size_t)g * 16 + r) * COUT + cc] = acc;
    }
}

extern "C" void kernel_launch(void* const* d_in, const int* in_sizes, int n_in,
                              void* d_out, int out_size, void* d_ws, size_t ws_size,
                              hipStream_t stream)
{
    const float* x   = (const float*)d_in[0];
    const float* E_w = (const float*)d_in[1];
    const float* E_b = (const float*)d_in[2];
    const float* B_p = (const float*)d_in[3];
    const float* C_p = (const float*)d_in[4];
    const float* D_w = (const float*)d_in[5];
    const float* D_b = (const float*)d_in[6];
    float* out = (float*)d_out;

    const int B  = out_size / COUT;            // 512
    const int T  = in_sizes[0] / (B * DIN);    // 1024
    const int NB = B / 16;                     // 32 blocks

    rnn_core<<<NB, 512, 0, stream>>>(x, E_w, E_b, B_p, C_p, D_w, D_b, out, T);
}

// Round 9
// 665.197 us; speedup vs baseline: 1.2278x; 1.2278x over previous
//
#include <hip/hip_runtime.h>

#define EPS_C 0.01f
#define NU    128
#define DIN   64
#define COUT  10
// 2*log2(e): folded into W, E_w, E_b so tanh arg arrives pre-scaled for exp2
#define TSCALE 2.8853900817779268f

typedef float    f32x4 __attribute__((ext_vector_type(4)));
typedef _Float16 f16x2 __attribute__((ext_vector_type(2)));
typedef _Float16 f16x4 __attribute__((ext_vector_type(4)));
typedef _Float16 f16x8 __attribute__((ext_vector_type(8)));

#define MFMA32(A, B, C) __builtin_amdgcn_mfma_f32_16x16x32_f16((A), (B), (C), 0, 0, 0)
// LDS-only barrier: vmcnt stays in flight across the per-step sync.
#define BAR() asm volatile("s_waitcnt lgkmcnt(0)\n\ts_barrier" ::: "memory")

// Transposed recurrence, state h' = h/eps:
//   h'(t+1) = h'(t) + A h(t) + tanh(W h(t) + z(t)),  h = eps*h'
// r7 post-mortem: wave specialization concatenated phases (676us) - reverted.
// r5 fit: step 1040 = sync 184 + work 856; MFMA region latency-bound (2-way
// ILP chains, ~39cyc dep latency). This round (same sync structure as r5):
//  - k-reduction SPLIT: each of W/A chains becomes two depth-2 halves
//    (kt{0,1}, kt{2,3}) + f32 add -> 4-way MFMA ILP (156 -> ~80 cyc/region)
//  - z(t+1) MFMAs moved to STEP TOP on x-frags prefetched into REGISTERS one
//    step earlier -> executes inside the post-barrier ds_read-hB latency
//  - trans (exp2/rcp) interleaved with A-chain MFMAs
// 4 waves (256 thr), wave w owns units [32w, 32w+32) = m-tiles 2w, 2w+1.
// mfma_f32_16x16x32_f16 layouts (HW-verified rounds 0-5):
//   A-op: A[m = lane&15][k = quad*8 + j]
//   B-op: B[k = quad*8 + j][n = lane&15]
//   D   : D[row = quad*4 + reg][col = lane&15]
// h exchange: unit u = 32w+16mt+4q+r, batch lid ->
//   hbuf[np][kt=w][(2mt+(q>>1))*16+lid][4(q&1)+r]  (f16x4 write; reads are
//   linear ds_read_b128, conflict-free)
__global__ __launch_bounds__(256, 1)
void rnn_core(const float* __restrict__ x,
              const float* __restrict__ E_w, const float* __restrict__ E_b,
              const float* __restrict__ B_p, const float* __restrict__ C_p,
              const float* __restrict__ D_w, const float* __restrict__ D_b,
              float* __restrict__ out, int T)
{
    const int tid  = threadIdx.x;
    const int lane = tid & 63;
    const int w    = tid >> 6;     // wave 0..3
    const int lid  = lane & 15;
    const int q    = lane >> 4;
    const int g    = blockIdx.x;   // batch group (16 rows)

    // xs[buf]: 8 steps of x in B-frag layout: [t8][kt2][lane64][8 halves]
    __shared__ __attribute__((aligned(16))) _Float16 xs[2][8 * 1024];   // 2 x 16 KB
    __shared__ __attribute__((aligned(16))) _Float16 hbuf[2][4][64][8]; // 8 KB
    __shared__ float hfin[16][NU + 4];

    // ---- one-time weight fragments (wave w: m = 32w + 16mt + lid) ----
    // WT/EF/ebv scaled by TSCALE (tanh arg pre-scale for direct exp2).
    f16x8 AT[2][4], WT[2][4], EF[2][2];
    f32x4 ebv[2];
    #pragma unroll
    for (int mt = 0; mt < 2; ++mt) {
        const int m = w * 32 + mt * 16 + lid;
        #pragma unroll
        for (int kt = 0; kt < 4; ++kt) {
            f16x8 fa, fw;
            #pragma unroll
            for (int j = 0; j < 8; ++j) {
                const int k  = kt * 32 + q * 8 + j;
                const float dg = (k == m) ? 0.01f : 0.0f;
                fa[j] = (_Float16)(B_p[k * NU + m] - 0.6f * B_p[m * NU + k] - dg);
                fw[j] = (_Float16)((C_p[k * NU + m] - 0.6f * C_p[m * NU + k] - dg) * TSCALE);
            }
            AT[mt][kt] = fa;  WT[mt][kt] = fw;
        }
        #pragma unroll
        for (int kt = 0; kt < 2; ++kt) {
            f16x8 fe;
            #pragma unroll
            for (int j = 0; j < 8; ++j)
                fe[j] = (_Float16)(E_w[m * DIN + kt * 32 + q * 8 + j] * TSCALE);
            EF[mt][kt] = fe;
        }
        #pragma unroll
        for (int r = 0; r < 4; ++r)
            ebv[mt][r] = E_b[w * 32 + mt * 16 + q * 4 + r] * TSCALE;
    }

    // ---- x staging mapping (256 loader threads, 1 float4/step) ----
    const int bb = tid & 15;        // batch row
    const int s2 = tid >> 4;        // d-quad 0..15
    const float* xrow = x + ((size_t)(g * 16 + bb) * T) * DIN + s2 * 4;
    const int wb2 = (((s2 >> 3) * 64) + (((s2 >> 1) & 3) * 16) + bb) * 16 + (s2 & 1) * 8;

    float4 xg[8];   // one chunk = 8 steps

#define STAGE_WRITE(BUF)                                                      \
    {                                                                         \
        char* base_ = (char*)&xs[(BUF)][0];                                   \
        _Pragma("unroll")                                                     \
        for (int i2 = 0; i2 < 8; ++i2) {                                      \
            float4 v_ = xg[i2];                                               \
            f16x4 h4_;                                                        \
            h4_[0] = (_Float16)v_.x; h4_[1] = (_Float16)v_.y;                 \
            h4_[2] = (_Float16)v_.z; h4_[3] = (_Float16)v_.w;                 \
            *(f16x4*)(base_ + i2 * 2048 + wb2) = h4_;                         \
        }                                                                     \
    }

    // ---- init: zero parity-0 h buffer; stage chunk 0 ----
    ((float4*)&hbuf[0][0][0][0])[tid] = (float4){0.f, 0.f, 0.f, 0.f};
    #pragma unroll
    for (int i = 0; i < 8; ++i)
        xg[i] = *(const float4*)(xrow + (size_t)i * DIN);
    STAGE_WRITE(0)
    __syncthreads();

    // precomputed LDS byte bases (layout algebra verified r0/r1)
    char* xsb = (char*)&xs[0][0] + lane * 16;     // +buf*16384 +it*2048 +kt*1024
    char* hrb = (char*)&hbuf[0][0][0][0] + lane * 16;  // +p*4096 +kt*1024
    char* hwb = (char*)&hbuf[0][0][0][0]
              + (w * 64 + (q >> 1) * 16 + lid) * 16 + (q & 1) * 8;  // +np*4096 +mt*512

    const f32x4 zero4 = {0.f, 0.f, 0.f, 0.f};

    // ---- state: h' = 0; zc = scaled z(0); xfr[1] = x(1) frags ----
    f32x4 hf[2] = {zero4, zero4};
    f32x4 zc0, zc1;
    f16x8 xfr[2][2];    // register x-frag pipeline: slot[(t+1)&1] = x(t+1)
    {
        f16x8 x0 = *(const f16x8*)(xsb);
        f16x8 x1 = *(const f16x8*)(xsb + 1024);
        zc0 = ebv[0];
        zc0 = MFMA32(EF[0][0], x0, zc0);
        zc0 = MFMA32(EF[0][1], x1, zc0);
        zc1 = ebv[1];
        zc1 = MFMA32(EF[1][0], x0, zc1);
        zc1 = MFMA32(EF[1][1], x1, zc1);
        const int t1 = (T > 1) ? 1 : 0;
        char* xb1 = xsb + ((t1 >> 3) & 1) * 16384 + (t1 & 7) * 2048;
        xfr[1][0] = *(const f16x8*)(xb1);
        xfr[1][1] = *(const f16x8*)(xb1 + 1024);
    }

    const int nch = T >> 3;   // 128 chunks of 8 steps
    for (int c = 0; c < nch; ++c) {
        if (c + 1 < nch) {
            const float* xr2 = xrow + (size_t)(c + 1) * 8 * DIN;
            #pragma unroll
            for (int i = 0; i < 8; ++i)
                xg[i] = *(const float4*)(xr2 + (size_t)i * DIN);
        }
        #pragma unroll
        for (int i = 0; i < 8; ++i) {
            const int t  = c * 8 + i;
            const int p  = i & 1;
            const int np = p ^ 1;
            const int sc = (t + 1) & 1;   // slot holding x(t+1) frags (regs)
            const int sn = t & 1;         // slot to fill with x(t+2)

            // ---- issue LDS reads: hB(t) + x(t+2) frags (consumed next step)
            f16x8 hB[4];
            #pragma unroll
            for (int kt = 0; kt < 4; ++kt)
                hB[kt] = *(const f16x8*)(hrb + p * 4096 + kt * 1024);
            {
                int t2 = t + 2; if (t2 >= T) t2 = T - 1;
                char* xb2 = xsb + ((t2 >> 3) & 1) * 16384 + (t2 & 7) * 2048;
                xfr[sn][0] = *(const f16x8*)(xb2);
                xfr[sn][1] = *(const f16x8*)(xb2 + 1024);
            }

            // ---- z(t+1) chains on REGISTER x-frags: fills hB read latency
            f32x4 zn0 = ebv[0], zn1 = ebv[1];
            zn0 = MFMA32(EF[0][0], xfr[sc][0], zn0);
            zn1 = MFMA32(EF[1][0], xfr[sc][0], zn1);
            zn0 = MFMA32(EF[0][1], xfr[sc][1], zn0);
            zn1 = MFMA32(EF[1][1], xfr[sc][1], zn1);

            // ---- W region: 4 independent depth-2 chains + combine adds ----
            f32x4 wa0a = zc0, wa1a = zc1;
            f32x4 wa0b = zero4, wa1b = zero4;
            wa0a = MFMA32(WT[0][0], hB[0], wa0a);
            wa1a = MFMA32(WT[1][0], hB[0], wa1a);
            wa0b = MFMA32(WT[0][2], hB[2], wa0b);
            wa1b = MFMA32(WT[1][2], hB[2], wa1b);
            wa0a = MFMA32(WT[0][1], hB[1], wa0a);
            wa1a = MFMA32(WT[1][1], hB[1], wa1a);
            wa0b = MFMA32(WT[0][3], hB[3], wa0b);
            wa1b = MFMA32(WT[1][3], hB[3], wa1b);
            f32x4 wa0 = wa0a + wa0b;
            f32x4 wa1 = wa1a + wa1b;

            // ---- trans interleaved with A region (4 indep depth-2 chains)
            f32x4 e0, e1;
            #pragma unroll
            for (int r = 0; r < 4; ++r) e0[r] = __builtin_amdgcn_exp2f(wa0[r]);
            f32x4 ya0a = MFMA32(AT[0][0], hB[0], hf[0]);
            f32x4 ya1a = MFMA32(AT[1][0], hB[0], hf[1]);
            #pragma unroll
            for (int r = 0; r < 4; ++r) e1[r] = __builtin_amdgcn_exp2f(wa1[r]);
            f32x4 ya0b = MFMA32(AT[0][2], hB[2], zero4);
            f32x4 ya1b = MFMA32(AT[1][2], hB[2], zero4);
            f32x4 rc0, rc1;
            #pragma unroll
            for (int r = 0; r < 4; ++r) rc0[r] = __builtin_amdgcn_rcpf(e0[r] + 1.0f);
            ya0a = MFMA32(AT[0][1], hB[1], ya0a);
            ya1a = MFMA32(AT[1][1], hB[1], ya1a);
            #pragma unroll
            for (int r = 0; r < 4; ++r) rc1[r] = __builtin_amdgcn_rcpf(e1[r] + 1.0f);
            ya0b = MFMA32(AT[0][3], hB[3], ya0b);
            ya1b = MFMA32(AT[1][3], hB[3], ya1b);

            // ---- combine: h' = (yaa+yab) + 1 - 2*rc ; write f16(eps*h') ----
            hf[0] = ya0a + ya0b;
            hf[1] = ya1a + ya1b;
            #pragma unroll
            for (int r = 0; r < 4; ++r) {
                hf[0][r] = __builtin_fmaf(-2.0f, rc0[r], hf[0][r] + 1.0f);
                hf[1][r] = __builtin_fmaf(-2.0f, rc1[r], hf[1][r] + 1.0f);
            }
            #pragma unroll
            for (int mt = 0; mt < 2; ++mt) {
                f16x2 lo = __builtin_bit_cast(f16x2,
                    __builtin_amdgcn_cvt_pkrtz(EPS_C * hf[mt][0], EPS_C * hf[mt][1]));
                f16x2 hi = __builtin_bit_cast(f16x2,
                    __builtin_amdgcn_cvt_pkrtz(EPS_C * hf[mt][2], EPS_C * hf[mt][3]));
                f16x4 nh;
                nh[0] = lo[0]; nh[1] = lo[1]; nh[2] = hi[0]; nh[3] = hi[1];
                *(f16x4*)(hwb + np * 4096 + mt * 512) = nh;
            }
            zc0 = zn0; zc1 = zn1;

            if (i == 5 && c + 1 < nch) STAGE_WRITE((c + 1) & 1)
            BAR();   // lgkmcnt(0) + s_barrier; x prefetch loads stay in flight
        }
    }

    // ---- final: stash h = eps*h', small output GEMM ----
    #pragma unroll
    for (int mt = 0; mt < 2; ++mt)
        #pragma unroll
        for (int r = 0; r < 4; ++r)
            hfin[lid][w * 32 + mt * 16 + q * 4 + r] = EPS_C * hf[mt][r];
    __syncthreads();

    if (tid < 16 * COUT) {
        const int r  = tid / COUT;
        const int cc = tid - r * COUT;
        float acc = D_b[cc];
        #pragma unroll 8
        for (int u = 0; u < NU; ++u)
            acc = fmaf(hfin[r][u], D_w[cc * NU + u], acc);
        out[((size_t)g * 16 + r) * COUT + cc] = acc;
    }
}

extern "C" void kernel_launch(void* const* d_in, const int* in_sizes, int n_in,
                              void* d_out, int out_size, void* d_ws, size_t ws_size,
                              hipStream_t stream)
{
    const float* x   = (const float*)d_in[0];
    const float* E_w = (const float*)d_in[1];
    const float* E_b = (const float*)d_in[2];
    const float* B_p = (const float*)d_in[3];
    const float* C_p = (const float*)d_in[4];
    const float* D_w = (const float*)d_in[5];
    const float* D_b = (const float*)d_in[6];
    float* out = (float*)d_out;

    const int B  = out_size / COUT;            // 512
    const int T  = in_sizes[0] / (B * DIN);    // 1024
    const int NB = B / 16;                     // 32 blocks

    rnn_core<<<NB, 256, 0, stream>>>(x, E_w, E_b, B_p, C_p, D_w, D_b, out, T);
}